// Round 4
// baseline (617.983 us; speedup 1.0000x reference)
//
#include <hip/hip_runtime.h>
#include <math.h>

#define NN 8192
// out = elu(0.5*h_s + (sum_j w_ij h_n_j)/Z_i), w_ij = adj_ij * exp(relu(s_i+n_j))

typedef short short8 __attribute__((ext_vector_type(8)));   // 8 bf16 (4 VGPRs)
typedef float f32x4 __attribute__((ext_vector_type(4)));

__device__ __forceinline__ float eluf(float x) {
  return x > 0.f ? x : (__expf(x) - 1.f);
}
__device__ __forceinline__ unsigned short f2bf(float f) {
  union { float f; unsigned u; } v; v.f = f;
  unsigned r = v.u + 0x7fffu + ((v.u >> 16) & 1u);  // RNE
  return (unsigned short)(r >> 16);
}

// ---------------- Kernel 0: adj (int32 0/1, 256 MB) -> bitmask (8 MB) ----------------
// Ballot-packed, fully coalesced: per c-iter each wave does ONE 256B coalesced
// dword load + ONE __ballot; bit ln of the ballot IS bit j=wv*2048+c*64+ln.
// Lane 2c keeps the low word, lane 2c+1 the high word; one coalesced store/wave.
__global__ __launch_bounds__(256) void k_pack(const int* __restrict__ A,
                                              unsigned* __restrict__ P) {
  const int t = threadIdx.x, ln = t & 63, wv = t >> 6;
  const int row = blockIdx.x;  // 8192
  const int* src = A + (size_t)row * NN + wv * 2048 + ln;
  unsigned myw = 0;
#pragma unroll
  for (int c = 0; c < 32; ++c) {
    int a = src[c * 64];
    unsigned long long m = __ballot(a & 1);
    if (ln == 2 * c)     myw = (unsigned)m;
    if (ln == 2 * c + 1) myw = (unsigned)(m >> 32);
  }
  P[(size_t)row * 256 + wv * 64 + ln] = myw;
}

// ---------------- Kernel 1: projections + fused s/n reductions ----------------
// 8 rows/block, block 256, grid 1024. HnT output is j-block-major
// [NN/8][128 f][8 j] bf16 so k_main's 8 B-frag loads per 32-j step share ONE
// lane base + imm offsets and coalesce to 256B segments per quad.
__global__ __launch_bounds__(256) void k_proj(const float* __restrict__ X,
                                              const float* __restrict__ Ws,
                                              const float* __restrict__ Wn,
                                              const float* __restrict__ as_,
                                              const float* __restrict__ an_,
                                              float* __restrict__ Hs,
                                              unsigned short* __restrict__ HnT,
                                              float* __restrict__ s_out,
                                              float* __restrict__ n_out) {
  __shared__ float4 lin4[8 * 64];  // 8 rows x 256 f32 = 8 KB
  const int t = threadIdx.x;
  const int i0 = blockIdx.x * 8;
  const float4* Xg = (const float4*)X + (size_t)i0 * 64;
  lin4[t] = Xg[t];
  if (t < 256) lin4[t + 256] = Xg[t + 256];
  __syncthreads();
  const int c = t & 127;
  const int rh = t >> 7;  // 0..1, 4 rows each
  float accs[4], accn[4];
#pragma unroll
  for (int r = 0; r < 4; ++r) { accs[r] = 0.f; accn[r] = 0.f; }
  for (int k = 0; k < 256; k += 4) {
    float ws0 = Ws[(k + 0) * 128 + c], ws1 = Ws[(k + 1) * 128 + c];
    float ws2 = Ws[(k + 2) * 128 + c], ws3 = Ws[(k + 3) * 128 + c];
    float wn0 = Wn[(k + 0) * 128 + c], wn1 = Wn[(k + 1) * 128 + c];
    float wn2 = Wn[(k + 2) * 128 + c], wn3 = Wn[(k + 3) * 128 + c];
#pragma unroll
    for (int r = 0; r < 4; ++r) {
      float4 iv = lin4[(rh * 4 + r) * 64 + (k >> 2)];  // wave-uniform broadcast
      accs[r] = fmaf(iv.x, ws0, accs[r]); accs[r] = fmaf(iv.y, ws1, accs[r]);
      accs[r] = fmaf(iv.z, ws2, accs[r]); accs[r] = fmaf(iv.w, ws3, accs[r]);
      accn[r] = fmaf(iv.x, wn0, accn[r]); accn[r] = fmaf(iv.y, wn1, accn[r]);
      accn[r] = fmaf(iv.z, wn2, accn[r]); accn[r] = fmaf(iv.w, wn3, accn[r]);
    }
  }
  // Hs fp32 out
#pragma unroll
  for (int r = 0; r < 4; ++r)
    Hs[(size_t)(i0 + rh * 4 + r) * 128 + c] = accs[r];
  // HnT bf16 out, j-block-major: elem(jb=j/8, f, ji=j%8) at jb*1024 + f*8 + ji.
  {
    union { unsigned short us[4]; ushort4 u4; } pk;
#pragma unroll
    for (int r = 0; r < 4; ++r) pk.us[r] = f2bf(accn[r]);
    *(ushort4*)(HnT + (size_t)blockIdx.x * 1024 + c * 8 + rh * 4) = pk.u4;
  }
  // ---- fused reductions: s[j] = sum_f Hs[j][f]*a_s[f], n likewise ----
  float* red = (float*)lin4;  // 8 x 128 f32 = 4 KB
  const int wv = t >> 6, ln = t & 63;
  __syncthreads();
  {
    float av = as_[c];
#pragma unroll
    for (int r = 0; r < 4; ++r) red[(rh * 4 + r) * 128 + c] = accs[r] * av;
  }
  __syncthreads();
#pragma unroll
  for (int h = 0; h < 2; ++h) {
    int row = wv * 2 + h;
    float p = red[row * 128 + ln] + red[row * 128 + 64 + ln];
#pragma unroll
    for (int off = 32; off >= 1; off >>= 1) p += __shfl_down(p, off);
    if (ln == 0) s_out[i0 + row] = p;
  }
  __syncthreads();
  {
    float av = an_[c];
#pragma unroll
    for (int r = 0; r < 4; ++r) red[(rh * 4 + r) * 128 + c] = accn[r] * av;
  }
  __syncthreads();
#pragma unroll
  for (int h = 0; h < 2; ++h) {
    int row = wv * 2 + h;
    float p = red[row * 128 + ln] + red[row * 128 + 64 + ln];
#pragma unroll
    for (int off = 32; off >= 1; off >>= 1) p += __shfl_down(p, off);
    if (ln == 0) n_out[i0 + row] = p;
  }
}

// ---------------- Kernel 2: attention GEMM + softmax + elu ----------------
// Block 512 (8 waves), 16 rows/block, grid 512. nv (32 KB) and bits (16 KB)
// are staged into LDS in one coalesced prologue burst (region aliased with
// the epilogue's 64 KB accbuf), so the steady-state loop has EXACTLY ONE
// VMEM class (breg = HnT f-tiles from L2) and zero branches: the compiler's
// FIFO vmcnt wait for breg(tt) never drains a deeper prefetch. Last
// iteration peeled. breg(tt+1) issued split-half between the MFMA halves
// for ~220cy lead without register double-buffering.
__global__ __launch_bounds__(512, 4) void k_main_bits(const unsigned* __restrict__ Pk,
                                                      const unsigned short* __restrict__ HnT,
                                                      const float* __restrict__ sv_g,
                                                      const float* __restrict__ nv_g,
                                                      float* __restrict__ HsOut) {
  __shared__ __align__(16) char smem[65536];
  float* nv_lds = (float*)smem;                        // 8192 f32 = 32 KB (loop)
  unsigned* bits_lds = (unsigned*)(smem + 32768);      // 4096 u32 = 16 KB (loop)
  float* accbuf = (float*)smem;                        // 8*16*128 f32 = 64 KB (epilogue)
  __shared__ float zsh[8][16];
  __shared__ float zf[16];

  const int t = threadIdx.x;
  const int wv = t >> 6;   // wave 0..7 = j-partition
  const int ln = t & 63;
  const int q = ln >> 4;   // quad -> k-slice within K=32
  const int m = ln & 15;   // A row / B col / C col
  const int row0 = blockIdx.x * 16;

  // ---- prologue: cooperative stage of nv (8192 f32) and bits (16x256 u32) ----
  {
    float4* dst = (float4*)nv_lds;
    const float4* s4 = (const float4*)nv_g;
#pragma unroll
    for (int k = 0; k < 4; ++k) dst[t + k * 512] = s4[t + k * 512];
#pragma unroll
    for (int k = 0; k < 8; ++k) {
      int g = t + k * 512;            // 0..4095
      int rr = g >> 8;                // row-in-block 0..15
      int c8 = g & 255;               // word-in-row
      unsigned w = Pk[(size_t)(row0 + rr) * 256 + c8];
      // LDS layout [wv][tt][m]: conflict-free 16-bank read per step
      bits_lds[(c8 >> 5) * 512 + (c8 & 31) * 16 + rr] = w;
    }
  }

  const float sm = sv_g[row0 + m];
  // HnT elem(jb, f, ji) at jb*1024 + f*8 + ji ; lane base: jb = wv*128 + q, f = m
  const unsigned short* bp = HnT + ((size_t)(wv * 128 + q) * 128 + m) * 8;
  const float* nvl = nv_lds + wv * 1024 + q * 8;       // + tt*32
  const unsigned* bts = bits_lds + wv * 512 + m;       // + tt*16

  f32x4 acc[8];
#pragma unroll
  for (int ft = 0; ft < 8; ++ft) acc[ft] = (f32x4){0.f, 0.f, 0.f, 0.f};
  float zp = 0.f;

  union Breg { uint4 u; short8 s; };
  Breg breg[8];

  __syncthreads();  // LDS stage complete

  // breg(0)
  breg[0].u = *(const uint4*)(bp);       breg[1].u = *(const uint4*)(bp + 128);
  breg[2].u = *(const uint4*)(bp + 256); breg[3].u = *(const uint4*)(bp + 384);
  breg[4].u = *(const uint4*)(bp + 512); breg[5].u = *(const uint4*)(bp + 640);
  breg[6].u = *(const uint4*)(bp + 768); breg[7].u = *(const uint4*)(bp + 896);

#pragma unroll 2
  for (int tt = 0; tt < 31; ++tt) {
    // ---- A-frag from LDS: w for rows m, j = wv*1024 + tt*32 + q*8 .. +7 ----
    short8 fr;
    {
      float4 nv0 = *(const float4*)(nvl + tt * 32);
      float4 nv1 = *(const float4*)(nvl + tt * 32 + 4);
      const unsigned bw = bts[tt * 16];
      const unsigned byte = (bw >> (q * 8)) & 0xffu;
      float nvlv[8] = {nv0.x, nv0.y, nv0.z, nv0.w, nv1.x, nv1.y, nv1.z, nv1.w};
#pragma unroll
      for (int k = 0; k < 8; ++k) {
        float w = ((byte >> k) & 1u) ? __expf(fmaxf(sm + nvlv[k], 0.f)) : 0.f;
        zp += w;
        fr[k] = (short)f2bf(w);
      }
    }
    const unsigned short* np = bp + 4096;  // breg(tt+1) base (+4 j-blocks)
    // ---- MFMA first half; then issue breg0-3(tt+1) (regs free after consume) ----
    __builtin_amdgcn_s_setprio(1);
    acc[0] = __builtin_amdgcn_mfma_f32_16x16x32_bf16(fr, breg[0].s, acc[0], 0, 0, 0);
    acc[1] = __builtin_amdgcn_mfma_f32_16x16x32_bf16(fr, breg[1].s, acc[1], 0, 0, 0);
    acc[2] = __builtin_amdgcn_mfma_f32_16x16x32_bf16(fr, breg[2].s, acc[2], 0, 0, 0);
    acc[3] = __builtin_amdgcn_mfma_f32_16x16x32_bf16(fr, breg[3].s, acc[3], 0, 0, 0);
    breg[0].u = *(const uint4*)(np);       breg[1].u = *(const uint4*)(np + 128);
    breg[2].u = *(const uint4*)(np + 256); breg[3].u = *(const uint4*)(np + 384);
    acc[4] = __builtin_amdgcn_mfma_f32_16x16x32_bf16(fr, breg[4].s, acc[4], 0, 0, 0);
    acc[5] = __builtin_amdgcn_mfma_f32_16x16x32_bf16(fr, breg[5].s, acc[5], 0, 0, 0);
    acc[6] = __builtin_amdgcn_mfma_f32_16x16x32_bf16(fr, breg[6].s, acc[6], 0, 0, 0);
    acc[7] = __builtin_amdgcn_mfma_f32_16x16x32_bf16(fr, breg[7].s, acc[7], 0, 0, 0);
    __builtin_amdgcn_s_setprio(0);
    breg[4].u = *(const uint4*)(np + 512); breg[5].u = *(const uint4*)(np + 640);
    breg[6].u = *(const uint4*)(np + 768); breg[7].u = *(const uint4*)(np + 896);
    bp = np;
  }
  // ---- peeled tt = 31 (no prefetch) ----
  {
    short8 fr;
    {
      float4 nv0 = *(const float4*)(nvl + 31 * 32);
      float4 nv1 = *(const float4*)(nvl + 31 * 32 + 4);
      const unsigned bw = bts[31 * 16];
      const unsigned byte = (bw >> (q * 8)) & 0xffu;
      float nvlv[8] = {nv0.x, nv0.y, nv0.z, nv0.w, nv1.x, nv1.y, nv1.z, nv1.w};
#pragma unroll
      for (int k = 0; k < 8; ++k) {
        float w = ((byte >> k) & 1u) ? __expf(fmaxf(sm + nvlv[k], 0.f)) : 0.f;
        zp += w;
        fr[k] = (short)f2bf(w);
      }
    }
    __builtin_amdgcn_s_setprio(1);
    acc[0] = __builtin_amdgcn_mfma_f32_16x16x32_bf16(fr, breg[0].s, acc[0], 0, 0, 0);
    acc[1] = __builtin_amdgcn_mfma_f32_16x16x32_bf16(fr, breg[1].s, acc[1], 0, 0, 0);
    acc[2] = __builtin_amdgcn_mfma_f32_16x16x32_bf16(fr, breg[2].s, acc[2], 0, 0, 0);
    acc[3] = __builtin_amdgcn_mfma_f32_16x16x32_bf16(fr, breg[3].s, acc[3], 0, 0, 0);
    acc[4] = __builtin_amdgcn_mfma_f32_16x16x32_bf16(fr, breg[4].s, acc[4], 0, 0, 0);
    acc[5] = __builtin_amdgcn_mfma_f32_16x16x32_bf16(fr, breg[5].s, acc[5], 0, 0, 0);
    acc[6] = __builtin_amdgcn_mfma_f32_16x16x32_bf16(fr, breg[6].s, acc[6], 0, 0, 0);
    acc[7] = __builtin_amdgcn_mfma_f32_16x16x32_bf16(fr, breg[7].s, acc[7], 0, 0, 0);
    __builtin_amdgcn_s_setprio(0);
  }

  // ---- per-wave Z partial for each row m: reduce over q ----
  {
    float zz = zp;
    zz += __shfl_down(zz, 32);
    zz += __shfl_down(zz, 16);
    if (ln < 16) zsh[wv][ln] = zz;
  }
  __syncthreads();  // all waves done reading nv/bits LDS; zsh ready
  // ---- dump per-wave acc partials into (re-used) accbuf; col=m, row=q*4+reg ----
#pragma unroll
  for (int ft = 0; ft < 8; ++ft) {
#pragma unroll
    for (int reg = 0; reg < 4; ++reg)
      accbuf[wv * 2048 + (q * 4 + reg) * 128 + ft * 16 + m] = acc[ft][reg];
  }
  if (t < 16) {
    float z = zsh[0][t] + zsh[1][t] + zsh[2][t] + zsh[3][t] +
              zsh[4][t] + zsh[5][t] + zsh[6][t] + zsh[7][t];
    zf[t] = 1.f / z;
  }
  __syncthreads();
  // ---- combine 8 wave-partials + epilogue: out = elu(0.5*h_s + acc/Z) ----
  {
    const int row = t >> 5;        // 0..15
    const int f0 = (t & 31) * 4;   // 0..124
    f32x4 ssum = *(const f32x4*)&accbuf[row * 128 + f0];
#pragma unroll
    for (int w = 1; w < 8; ++w) ssum += *(const f32x4*)&accbuf[w * 2048 + row * 128 + f0];
    const float invz = zf[row];
    const size_t off = (size_t)(row0 + row) * 128 + f0;
    float4 h = *(const float4*)(HsOut + off);
    float4 o;
    o.x = eluf(fmaf(ssum[0], invz, 0.5f * h.x));
    o.y = eluf(fmaf(ssum[1], invz, 0.5f * h.y));
    o.z = eluf(fmaf(ssum[2], invz, 0.5f * h.z));
    o.w = eluf(fmaf(ssum[3], invz, 0.5f * h.w));
    *(float4*)(HsOut + off) = o;
  }
}

// ---------------- Kernel 2 (fallback if ws too small, R1-verified) -----------
__global__ __launch_bounds__(512, 4) void k_main_adj(const int* __restrict__ A,
                                                     const unsigned short* __restrict__ HnT,
                                                     const float* __restrict__ sv_g,
                                                     const float* __restrict__ nv_g,
                                                     float* __restrict__ HsOut) {
  __shared__ float accbuf[8][16][128];
  __shared__ float zsh[8][16];
  __shared__ float zf[16];

  const int t = threadIdx.x;
  const int wv = t >> 6;
  const int ln = t & 63;
  const int q = ln >> 4;
  const int m = ln & 15;
  const int row0 = blockIdx.x * 16;

  const float sm = sv_g[row0 + m];
  const int jbase = wv * 1024 + q * 8;
  const int* aptr = A + (size_t)(row0 + m) * NN + jbase;
  const float* nptr = nv_g + jbase;
  const unsigned short* bptr = HnT + ((size_t)(wv * 128 + q) * 128 + m) * 8;

  f32x4 acc[8];
#pragma unroll
  for (int ft = 0; ft < 8; ++ft) acc[ft] = (f32x4){0.f, 0.f, 0.f, 0.f};
  float zp = 0.f;

  int4 adjv[2][2];
  float4 nvv[2][2];
  union Breg { uint4 u; short8 s; };
  Breg breg[8];

  adjv[0][0] = *(const int4*)(aptr);       adjv[0][1] = *(const int4*)(aptr + 4);
  adjv[1][0] = *(const int4*)(aptr + 32);  adjv[1][1] = *(const int4*)(aptr + 36);
  nvv[0][0] = *(const float4*)(nptr);      nvv[0][1] = *(const float4*)(nptr + 4);
  breg[0].u = *(const uint4*)(bptr);       breg[1].u = *(const uint4*)(bptr + 128);
  breg[2].u = *(const uint4*)(bptr + 256); breg[3].u = *(const uint4*)(bptr + 384);
  breg[4].u = *(const uint4*)(bptr + 512); breg[5].u = *(const uint4*)(bptr + 640);
  breg[6].u = *(const uint4*)(bptr + 768); breg[7].u = *(const uint4*)(bptr + 896);

#pragma unroll 2
  for (int tt = 0; tt < 32; ++tt) {
    const int cur = tt & 1;
    short8 fr;
    {
      float nvl[8] = {nvv[cur][0].x, nvv[cur][0].y, nvv[cur][0].z, nvv[cur][0].w,
                      nvv[cur][1].x, nvv[cur][1].y, nvv[cur][1].z, nvv[cur][1].w};
      int av[8] = {adjv[cur][0].x, adjv[cur][0].y, adjv[cur][0].z, adjv[cur][0].w,
                   adjv[cur][1].x, adjv[cur][1].y, adjv[cur][1].z, adjv[cur][1].w};
#pragma unroll
      for (int k = 0; k < 8; ++k) {
        float w = av[k] > 0 ? __expf(fmaxf(sm + nvl[k], 0.f)) : 0.f;
        zp += w;
        fr[k] = (short)f2bf(w);
      }
    }
    if (tt < 31) {
      const float* p = nptr + (tt + 1) * 32;
      nvv[cur ^ 1][0] = *(const float4*)p;
      nvv[cur ^ 1][1] = *(const float4*)(p + 4);
    }
    __builtin_amdgcn_s_setprio(1);
    acc[0] = __builtin_amdgcn_mfma_f32_16x16x32_bf16(fr, breg[0].s, acc[0], 0, 0, 0);
    acc[1] = __builtin_amdgcn_mfma_f32_16x16x32_bf16(fr, breg[1].s, acc[1], 0, 0, 0);
    acc[2] = __builtin_amdgcn_mfma_f32_16x16x32_bf16(fr, breg[2].s, acc[2], 0, 0, 0);
    acc[3] = __builtin_amdgcn_mfma_f32_16x16x32_bf16(fr, breg[3].s, acc[3], 0, 0, 0);
    acc[4] = __builtin_amdgcn_mfma_f32_16x16x32_bf16(fr, breg[4].s, acc[4], 0, 0, 0);
    acc[5] = __builtin_amdgcn_mfma_f32_16x16x32_bf16(fr, breg[5].s, acc[5], 0, 0, 0);
    acc[6] = __builtin_amdgcn_mfma_f32_16x16x32_bf16(fr, breg[6].s, acc[6], 0, 0, 0);
    acc[7] = __builtin_amdgcn_mfma_f32_16x16x32_bf16(fr, breg[7].s, acc[7], 0, 0, 0);
    __builtin_amdgcn_s_setprio(0);
    if (tt < 31) {
      const unsigned short* p = bptr + (size_t)(tt + 1) * 4096;
      breg[0].u = *(const uint4*)(p);       breg[1].u = *(const uint4*)(p + 128);
      breg[2].u = *(const uint4*)(p + 256); breg[3].u = *(const uint4*)(p + 384);
      breg[4].u = *(const uint4*)(p + 512); breg[5].u = *(const uint4*)(p + 640);
      breg[6].u = *(const uint4*)(p + 768); breg[7].u = *(const uint4*)(p + 896);
    }
    if (tt < 30) {
      const int* p = aptr + (tt + 2) * 32;
      adjv[cur][0] = *(const int4*)p;
      adjv[cur][1] = *(const int4*)(p + 4);
    }
  }

  {
    float zz = zp;
    zz += __shfl_down(zz, 32);
    zz += __shfl_down(zz, 16);
    if (ln < 16) zsh[wv][ln] = zz;
  }
#pragma unroll
  for (int ft = 0; ft < 8; ++ft) {
#pragma unroll
    for (int reg = 0; reg < 4; ++reg)
      accbuf[wv][q * 4 + reg][ft * 16 + m] = acc[ft][reg];
  }
  __syncthreads();
  if (t < 16) {
    float z = zsh[0][t] + zsh[1][t] + zsh[2][t] + zsh[3][t] +
              zsh[4][t] + zsh[5][t] + zsh[6][t] + zsh[7][t];
    zf[t] = 1.f / z;
  }
  __syncthreads();
  {
    const int row = t >> 5;
    const int f0 = (t & 31) * 4;
    f32x4 ssum = *(const f32x4*)&accbuf[0][row][f0];
#pragma unroll
    for (int w = 1; w < 8; ++w) ssum += *(const f32x4*)&accbuf[w][row][f0];
    const float invz = zf[row];
    const size_t off = (size_t)(row0 + row) * 128 + f0;
    float4 h = *(const float4*)(HsOut + off);
    float4 o;
    o.x = eluf(fmaf(ssum[0], invz, 0.5f * h.x));
    o.y = eluf(fmaf(ssum[1], invz, 0.5f * h.y));
    o.z = eluf(fmaf(ssum[2], invz, 0.5f * h.z));
    o.w = eluf(fmaf(ssum[3], invz, 0.5f * h.w));
    *(float4*)(HsOut + off) = o;
  }
}

extern "C" void kernel_launch(void* const* d_in, const int* in_sizes, int n_in,
                              void* d_out, int out_size, void* d_ws, size_t ws_size,
                              hipStream_t stream) {
  const float* X   = (const float*)d_in[0];
  const int*   A   = (const int*)d_in[1];
  const float* Ws  = (const float*)d_in[2];
  const float* as_ = (const float*)d_in[3];
  const float* Wn  = (const float*)d_in[4];
  const float* an_ = (const float*)d_in[5];
  float* out = (float*)d_out;  // holds h_s, then final output (in-place epilogue)

  unsigned short* HnT = (unsigned short*)d_ws;       // 2 MB (j-block-major)
  float* s = (float*)(HnT + (size_t)128 * NN);       // 8192 f32
  float* n = s + NN;                                 // 8192 f32
  unsigned* P = (unsigned*)(n + NN);                 // 8192*256 uint = 8 MB bitmask

  const size_t base_need = (size_t)128 * NN * 2 + (size_t)2 * NN * 4;
  const size_t bits_need = base_need + (size_t)NN * 256 * 4;

  k_proj<<<1024, 256, 0, stream>>>(X, Ws, Wn, as_, an_, out, HnT, s, n);
  if (ws_size >= bits_need) {
    k_pack<<<8192, 256, 0, stream>>>(A, P);
    k_main_bits<<<512, 512, 0, stream>>>(P, HnT, s, n, out);
  } else {
    k_main_adj<<<512, 512, 0, stream>>>(A, HnT, s, n, out);
  }
}

// Round 5
// 441.325 us; speedup vs baseline: 1.4003x; 1.4003x over previous
//
#include <hip/hip_runtime.h>
#include <math.h>

#define NN 8192
// out = elu(0.5*h_s + (sum_j w_ij h_n_j)/Z_i), w_ij = adj_ij * exp(relu(s_i+n_j))

typedef short short8 __attribute__((ext_vector_type(8)));   // 8 bf16 (4 VGPRs)
typedef float f32x4 __attribute__((ext_vector_type(4)));

__device__ __forceinline__ float eluf(float x) {
  return x > 0.f ? x : (__expf(x) - 1.f);
}
__device__ __forceinline__ unsigned short f2bf(float f) {
  union { float f; unsigned u; } v; v.f = f;
  unsigned r = v.u + 0x7fffu + ((v.u >> 16) & 1u);  // RNE
  return (unsigned short)(r >> 16);
}

// ---------------- Kernel 0: adj (int32 0/1, 256 MB) -> bitmask (8 MB) ----------------
// Verified R3 version. Each thread owns a 128-B chunk (8 int4 loads in flight);
// pure streaming, no dependent chains.
// Layout: P[row][j/32] uint, bit b of word = adj[row][seg*32 + b].
__global__ __launch_bounds__(256) void k_pack(const int* __restrict__ A,
                                              unsigned* __restrict__ P) {
  const int t = threadIdx.x;
  const int row = blockIdx.x;  // 8192
  const int4* src = (const int4*)(A + (size_t)row * NN) + t * 8;  // t*32 ints
  int4 v[8];
#pragma unroll
  for (int c = 0; c < 8; ++c) v[c] = src[c];  // 8 loads in flight
  unsigned w = 0;
#pragma unroll
  for (int c = 0; c < 8; ++c) {  // adj in {0,1} -> low bit IS the predicate
    w |= (unsigned)(v[c].x & 1) << (c * 4 + 0);
    w |= (unsigned)(v[c].y & 1) << (c * 4 + 1);
    w |= (unsigned)(v[c].z & 1) << (c * 4 + 2);
    w |= (unsigned)(v[c].w & 1) << (c * 4 + 3);
  }
  P[(size_t)row * 256 + t] = w;
}

// ---------------- Kernel 1: projections + fused s/n reductions ----------------
// Verified. 8 rows/block, block 256, grid 1024. HnT output is j-block-major
// [NN/8][128 f][8 j] bf16 so k_main's 8 B-frag loads per 32-j step share ONE
// lane base + imm offsets and coalesce to 256B segments per quad.
__global__ __launch_bounds__(256) void k_proj(const float* __restrict__ X,
                                              const float* __restrict__ Ws,
                                              const float* __restrict__ Wn,
                                              const float* __restrict__ as_,
                                              const float* __restrict__ an_,
                                              float* __restrict__ Hs,
                                              unsigned short* __restrict__ HnT,
                                              float* __restrict__ s_out,
                                              float* __restrict__ n_out) {
  __shared__ float4 lin4[8 * 64];  // 8 rows x 256 f32 = 8 KB
  const int t = threadIdx.x;
  const int i0 = blockIdx.x * 8;
  const float4* Xg = (const float4*)X + (size_t)i0 * 64;
  lin4[t] = Xg[t];
  if (t < 256) lin4[t + 256] = Xg[t + 256];
  __syncthreads();
  const int c = t & 127;
  const int rh = t >> 7;  // 0..1, 4 rows each
  float accs[4], accn[4];
#pragma unroll
  for (int r = 0; r < 4; ++r) { accs[r] = 0.f; accn[r] = 0.f; }
  for (int k = 0; k < 256; k += 4) {
    float ws0 = Ws[(k + 0) * 128 + c], ws1 = Ws[(k + 1) * 128 + c];
    float ws2 = Ws[(k + 2) * 128 + c], ws3 = Ws[(k + 3) * 128 + c];
    float wn0 = Wn[(k + 0) * 128 + c], wn1 = Wn[(k + 1) * 128 + c];
    float wn2 = Wn[(k + 2) * 128 + c], wn3 = Wn[(k + 3) * 128 + c];
#pragma unroll
    for (int r = 0; r < 4; ++r) {
      float4 iv = lin4[(rh * 4 + r) * 64 + (k >> 2)];  // wave-uniform broadcast
      accs[r] = fmaf(iv.x, ws0, accs[r]); accs[r] = fmaf(iv.y, ws1, accs[r]);
      accs[r] = fmaf(iv.z, ws2, accs[r]); accs[r] = fmaf(iv.w, ws3, accs[r]);
      accn[r] = fmaf(iv.x, wn0, accn[r]); accn[r] = fmaf(iv.y, wn1, accn[r]);
      accn[r] = fmaf(iv.z, wn2, accn[r]); accn[r] = fmaf(iv.w, wn3, accn[r]);
    }
  }
  // Hs fp32 out
#pragma unroll
  for (int r = 0; r < 4; ++r)
    Hs[(size_t)(i0 + rh * 4 + r) * 128 + c] = accs[r];
  // HnT bf16 out, j-block-major: elem(jb=j/8, f, ji=j%8) at jb*1024 + f*8 + ji.
  {
    union { unsigned short us[4]; ushort4 u4; } pk;
#pragma unroll
    for (int r = 0; r < 4; ++r) pk.us[r] = f2bf(accn[r]);
    *(ushort4*)(HnT + (size_t)blockIdx.x * 1024 + c * 8 + rh * 4) = pk.u4;
  }
  // ---- fused reductions: s[j] = sum_f Hs[j][f]*a_s[f], n likewise ----
  float* red = (float*)lin4;  // 8 x 128 f32 = 4 KB
  const int wv = t >> 6, ln = t & 63;
  __syncthreads();
  {
    float av = as_[c];
#pragma unroll
    for (int r = 0; r < 4; ++r) red[(rh * 4 + r) * 128 + c] = accs[r] * av;
  }
  __syncthreads();
#pragma unroll
  for (int h = 0; h < 2; ++h) {
    int row = wv * 2 + h;
    float p = red[row * 128 + ln] + red[row * 128 + 64 + ln];
#pragma unroll
    for (int off = 32; off >= 1; off >>= 1) p += __shfl_down(p, off);
    if (ln == 0) s_out[i0 + row] = p;
  }
  __syncthreads();
  {
    float av = an_[c];
#pragma unroll
    for (int r = 0; r < 4; ++r) red[(rh * 4 + r) * 128 + c] = accn[r] * av;
  }
  __syncthreads();
#pragma unroll
  for (int h = 0; h < 2; ++h) {
    int row = wv * 2 + h;
    float p = red[row * 128 + ln] + red[row * 128 + 64 + ln];
#pragma unroll
    for (int off = 32; off >= 1; off >>= 1) p += __shfl_down(p, off);
    if (ln == 0) n_out[i0 + row] = p;
  }
}

// ---------------- Kernel 2: attention GEMM + softmax + elu ----------------
// Block 512 (8 waves), 16 rows/block, grid 512. nv (32 KB) + bits (16 KB)
// staged to LDS in a coalesced prologue (region aliased with the epilogue's
// 64 KB accbuf). Steady-state loop: ONE VMEM class (breg = HnT f-tiles, L2-
// resident), ZERO branches (tt=31 prefetch harmlessly overruns into the
// adjacent s/n workspace region). breg schedule is the R1/R3-verified
// non-spilling one: single generation, all 8 loads issued AFTER the MFMA
// block, consumed next iteration after the fr-compute (which covers most of
// the L2 latency; 16 waves/CU TLP covers the rest).
__global__ __launch_bounds__(512, 4) void k_main_bits(const unsigned* __restrict__ Pk,
                                                      const unsigned short* __restrict__ HnT,
                                                      const float* __restrict__ sv_g,
                                                      const float* __restrict__ nv_g,
                                                      float* __restrict__ HsOut) {
  __shared__ __align__(16) char smem[65536];
  float* nv_lds = (float*)smem;                        // 8192 f32 = 32 KB (loop)
  unsigned* bits_lds = (unsigned*)(smem + 32768);      // 4096 u32 = 16 KB (loop)
  float* accbuf = (float*)smem;                        // 8*16*128 f32 = 64 KB (epilogue)
  __shared__ float zsh[8][16];
  __shared__ float zf[16];

  const int t = threadIdx.x;
  const int wv = t >> 6;   // wave 0..7 = j-partition
  const int ln = t & 63;
  const int q = ln >> 4;   // quad -> k-slice within K=32
  const int m = ln & 15;   // A row / B col / C col
  const int row0 = blockIdx.x * 16;

  // ---- prologue: cooperative stage of nv (8192 f32) and bits (16x256 u32) ----
  {
    float4* dst = (float4*)nv_lds;
    const float4* s4 = (const float4*)nv_g;
#pragma unroll
    for (int k = 0; k < 4; ++k) dst[t + k * 512] = s4[t + k * 512];
#pragma unroll
    for (int k = 0; k < 8; ++k) {
      int g = t + k * 512;            // 0..4095
      int rr = g >> 8;                // row-in-block 0..15
      int c8 = g & 255;               // word-in-row
      unsigned w = Pk[(size_t)(row0 + rr) * 256 + c8];
      // LDS layout [wv][tt][m]: conflict-free 16-bank broadcast read per step
      bits_lds[(c8 >> 5) * 512 + (c8 & 31) * 16 + rr] = w;
    }
  }

  const float sm = sv_g[row0 + m];
  // HnT elem(jb, f, ji) at jb*1024 + f*8 + ji ; lane base: jb = wv*128 + q, f = m
  const unsigned short* bptr = HnT + ((size_t)(wv * 128 + q) * 128 + m) * 8;
  const float* nvl = nv_lds + wv * 1024 + q * 8;       // + tt*32
  const unsigned* bts = bits_lds + wv * 512 + m;       // + tt*16

  f32x4 acc[8];
#pragma unroll
  for (int ft = 0; ft < 8; ++ft) acc[ft] = (f32x4){0.f, 0.f, 0.f, 0.f};
  float zp = 0.f;

  union Breg { uint4 u; short8 s; };
  Breg breg[8];

  __syncthreads();  // LDS stage complete

  // breg(0)
  breg[0].u = *(const uint4*)(bptr);       breg[1].u = *(const uint4*)(bptr + 128);
  breg[2].u = *(const uint4*)(bptr + 256); breg[3].u = *(const uint4*)(bptr + 384);
  breg[4].u = *(const uint4*)(bptr + 512); breg[5].u = *(const uint4*)(bptr + 640);
  breg[6].u = *(const uint4*)(bptr + 768); breg[7].u = *(const uint4*)(bptr + 896);

#pragma unroll 2
  for (int tt = 0; tt < 32; ++tt) {
    // ---- A-frag from LDS: w for rows m, j = wv*1024 + tt*32 + q*8 .. +7 ----
    short8 fr;
    {
      float4 nv0 = *(const float4*)(nvl + tt * 32);
      float4 nv1 = *(const float4*)(nvl + tt * 32 + 4);
      const unsigned bw = bts[tt * 16];
      const unsigned byte = (bw >> (q * 8)) & 0xffu;
      float nvlv[8] = {nv0.x, nv0.y, nv0.z, nv0.w, nv1.x, nv1.y, nv1.z, nv1.w};
#pragma unroll
      for (int k = 0; k < 8; ++k) {
        float w = ((byte >> k) & 1u) ? __expf(fmaxf(sm + nvlv[k], 0.f)) : 0.f;
        zp += w;
        fr[k] = (short)f2bf(w);
      }
    }
    // ---- MFMA: consumes breg(tt) issued last iteration ----
    __builtin_amdgcn_s_setprio(1);
    acc[0] = __builtin_amdgcn_mfma_f32_16x16x32_bf16(fr, breg[0].s, acc[0], 0, 0, 0);
    acc[1] = __builtin_amdgcn_mfma_f32_16x16x32_bf16(fr, breg[1].s, acc[1], 0, 0, 0);
    acc[2] = __builtin_amdgcn_mfma_f32_16x16x32_bf16(fr, breg[2].s, acc[2], 0, 0, 0);
    acc[3] = __builtin_amdgcn_mfma_f32_16x16x32_bf16(fr, breg[3].s, acc[3], 0, 0, 0);
    acc[4] = __builtin_amdgcn_mfma_f32_16x16x32_bf16(fr, breg[4].s, acc[4], 0, 0, 0);
    acc[5] = __builtin_amdgcn_mfma_f32_16x16x32_bf16(fr, breg[5].s, acc[5], 0, 0, 0);
    acc[6] = __builtin_amdgcn_mfma_f32_16x16x32_bf16(fr, breg[6].s, acc[6], 0, 0, 0);
    acc[7] = __builtin_amdgcn_mfma_f32_16x16x32_bf16(fr, breg[7].s, acc[7], 0, 0, 0);
    __builtin_amdgcn_s_setprio(0);
    // ---- issue breg(tt+1), branch-free; tt=31 overruns ~0.1 MB into the
    // adjacent s/n region of the same workspace (read-only, discarded) ----
    {
      const unsigned short* p = bptr + (size_t)(tt + 1) * 4096;  // +4 j-blocks
      breg[0].u = *(const uint4*)(p);       breg[1].u = *(const uint4*)(p + 128);
      breg[2].u = *(const uint4*)(p + 256); breg[3].u = *(const uint4*)(p + 384);
      breg[4].u = *(const uint4*)(p + 512); breg[5].u = *(const uint4*)(p + 640);
      breg[6].u = *(const uint4*)(p + 768); breg[7].u = *(const uint4*)(p + 896);
    }
  }

  // ---- per-wave Z partial for each row m: reduce over q ----
  {
    float zz = zp;
    zz += __shfl_down(zz, 32);
    zz += __shfl_down(zz, 16);
    if (ln < 16) zsh[wv][ln] = zz;
  }
  __syncthreads();  // all waves done reading nv/bits LDS; zsh ready
  // ---- dump per-wave acc partials into (re-used) accbuf; col=m, row=q*4+reg ----
#pragma unroll
  for (int ft = 0; ft < 8; ++ft) {
#pragma unroll
    for (int reg = 0; reg < 4; ++reg)
      accbuf[wv * 2048 + (q * 4 + reg) * 128 + ft * 16 + m] = acc[ft][reg];
  }
  if (t < 16) {
    float z = zsh[0][t] + zsh[1][t] + zsh[2][t] + zsh[3][t] +
              zsh[4][t] + zsh[5][t] + zsh[6][t] + zsh[7][t];
    zf[t] = 1.f / z;
  }
  __syncthreads();
  // ---- combine 8 wave-partials + epilogue: out = elu(0.5*h_s + acc/Z) ----
  {
    const int row = t >> 5;        // 0..15
    const int f0 = (t & 31) * 4;   // 0..124
    f32x4 ssum = *(const f32x4*)&accbuf[row * 128 + f0];
#pragma unroll
    for (int w = 1; w < 8; ++w) ssum += *(const f32x4*)&accbuf[w * 2048 + row * 128 + f0];
    const float invz = zf[row];
    const size_t off = (size_t)(row0 + row) * 128 + f0;
    float4 h = *(const float4*)(HsOut + off);
    float4 o;
    o.x = eluf(fmaf(ssum[0], invz, 0.5f * h.x));
    o.y = eluf(fmaf(ssum[1], invz, 0.5f * h.y));
    o.z = eluf(fmaf(ssum[2], invz, 0.5f * h.z));
    o.w = eluf(fmaf(ssum[3], invz, 0.5f * h.w));
    *(float4*)(HsOut + off) = o;
  }
}

// ---------------- Kernel 2 (fallback if ws too small, R1-verified) -----------
__global__ __launch_bounds__(512, 4) void k_main_adj(const int* __restrict__ A,
                                                     const unsigned short* __restrict__ HnT,
                                                     const float* __restrict__ sv_g,
                                                     const float* __restrict__ nv_g,
                                                     float* __restrict__ HsOut) {
  __shared__ float accbuf[8][16][128];
  __shared__ float zsh[8][16];
  __shared__ float zf[16];

  const int t = threadIdx.x;
  const int wv = t >> 6;
  const int ln = t & 63;
  const int q = ln >> 4;
  const int m = ln & 15;
  const int row0 = blockIdx.x * 16;

  const float sm = sv_g[row0 + m];
  const int jbase = wv * 1024 + q * 8;
  const int* aptr = A + (size_t)(row0 + m) * NN + jbase;
  const float* nptr = nv_g + jbase;
  const unsigned short* bptr = HnT + ((size_t)(wv * 128 + q) * 128 + m) * 8;

  f32x4 acc[8];
#pragma unroll
  for (int ft = 0; ft < 8; ++ft) acc[ft] = (f32x4){0.f, 0.f, 0.f, 0.f};
  float zp = 0.f;

  int4 adjv[2][2];
  float4 nvv[2][2];
  union Breg { uint4 u; short8 s; };
  Breg breg[8];

  adjv[0][0] = *(const int4*)(aptr);       adjv[0][1] = *(const int4*)(aptr + 4);
  adjv[1][0] = *(const int4*)(aptr + 32);  adjv[1][1] = *(const int4*)(aptr + 36);
  nvv[0][0] = *(const float4*)(nptr);      nvv[0][1] = *(const float4*)(nptr + 4);
  breg[0].u = *(const uint4*)(bptr);       breg[1].u = *(const uint4*)(bptr + 128);
  breg[2].u = *(const uint4*)(bptr + 256); breg[3].u = *(const uint4*)(bptr + 384);
  breg[4].u = *(const uint4*)(bptr + 512); breg[5].u = *(const uint4*)(bptr + 640);
  breg[6].u = *(const uint4*)(bptr + 768); breg[7].u = *(const uint4*)(bptr + 896);

#pragma unroll 2
  for (int tt = 0; tt < 32; ++tt) {
    const int cur = tt & 1;
    short8 fr;
    {
      float nvl[8] = {nvv[cur][0].x, nvv[cur][0].y, nvv[cur][0].z, nvv[cur][0].w,
                      nvv[cur][1].x, nvv[cur][1].y, nvv[cur][1].z, nvv[cur][1].w};
      int av[8] = {adjv[cur][0].x, adjv[cur][0].y, adjv[cur][0].z, adjv[cur][0].w,
                   adjv[cur][1].x, adjv[cur][1].y, adjv[cur][1].z, adjv[cur][1].w};
#pragma unroll
      for (int k = 0; k < 8; ++k) {
        float w = av[k] > 0 ? __expf(fmaxf(sm + nvl[k], 0.f)) : 0.f;
        zp += w;
        fr[k] = (short)f2bf(w);
      }
    }
    if (tt < 31) {
      const float* p = nptr + (tt + 1) * 32;
      nvv[cur ^ 1][0] = *(const float4*)p;
      nvv[cur ^ 1][1] = *(const float4*)(p + 4);
    }
    __builtin_amdgcn_s_setprio(1);
    acc[0] = __builtin_amdgcn_mfma_f32_16x16x32_bf16(fr, breg[0].s, acc[0], 0, 0, 0);
    acc[1] = __builtin_amdgcn_mfma_f32_16x16x32_bf16(fr, breg[1].s, acc[1], 0, 0, 0);
    acc[2] = __builtin_amdgcn_mfma_f32_16x16x32_bf16(fr, breg[2].s, acc[2], 0, 0, 0);
    acc[3] = __builtin_amdgcn_mfma_f32_16x16x32_bf16(fr, breg[3].s, acc[3], 0, 0, 0);
    acc[4] = __builtin_amdgcn_mfma_f32_16x16x32_bf16(fr, breg[4].s, acc[4], 0, 0, 0);
    acc[5] = __builtin_amdgcn_mfma_f32_16x16x32_bf16(fr, breg[5].s, acc[5], 0, 0, 0);
    acc[6] = __builtin_amdgcn_mfma_f32_16x16x32_bf16(fr, breg[6].s, acc[6], 0, 0, 0);
    acc[7] = __builtin_amdgcn_mfma_f32_16x16x32_bf16(fr, breg[7].s, acc[7], 0, 0, 0);
    __builtin_amdgcn_s_setprio(0);
    if (tt < 31) {
      const unsigned short* p = bptr + (size_t)(tt + 1) * 4096;
      breg[0].u = *(const uint4*)(p);       breg[1].u = *(const uint4*)(p + 128);
      breg[2].u = *(const uint4*)(p + 256); breg[3].u = *(const uint4*)(p + 384);
      breg[4].u = *(const uint4*)(p + 512); breg[5].u = *(const uint4*)(p + 640);
      breg[6].u = *(const uint4*)(p + 768); breg[7].u = *(const uint4*)(p + 896);
    }
    if (tt < 30) {
      const int* p = aptr + (tt + 2) * 32;
      adjv[cur][0] = *(const int4*)p;
      adjv[cur][1] = *(const int4*)(p + 4);
    }
  }

  {
    float zz = zp;
    zz += __shfl_down(zz, 32);
    zz += __shfl_down(zz, 16);
    if (ln < 16) zsh[wv][ln] = zz;
  }
#pragma unroll
  for (int ft = 0; ft < 8; ++ft) {
#pragma unroll
    for (int reg = 0; reg < 4; ++reg)
      accbuf[wv][q * 4 + reg][ft * 16 + m] = acc[ft][reg];
  }
  __syncthreads();
  if (t < 16) {
    float z = zsh[0][t] + zsh[1][t] + zsh[2][t] + zsh[3][t] +
              zsh[4][t] + zsh[5][t] + zsh[6][t] + zsh[7][t];
    zf[t] = 1.f / z;
  }
  __syncthreads();
  {
    const int row = t >> 5;
    const int f0 = (t & 31) * 4;
    f32x4 ssum = *(const f32x4*)&accbuf[0][row][f0];
#pragma unroll
    for (int w = 1; w < 8; ++w) ssum += *(const f32x4*)&accbuf[w][row][f0];
    const float invz = zf[row];
    const size_t off = (size_t)(row0 + row) * 128 + f0;
    float4 h = *(const float4*)(HsOut + off);
    float4 o;
    o.x = eluf(fmaf(ssum[0], invz, 0.5f * h.x));
    o.y = eluf(fmaf(ssum[1], invz, 0.5f * h.y));
    o.z = eluf(fmaf(ssum[2], invz, 0.5f * h.z));
    o.w = eluf(fmaf(ssum[3], invz, 0.5f * h.w));
    *(float4*)(HsOut + off) = o;
  }
}

extern "C" void kernel_launch(void* const* d_in, const int* in_sizes, int n_in,
                              void* d_out, int out_size, void* d_ws, size_t ws_size,
                              hipStream_t stream) {
  const float* X   = (const float*)d_in[0];
  const int*   A   = (const int*)d_in[1];
  const float* Ws  = (const float*)d_in[2];
  const float* as_ = (const float*)d_in[3];
  const float* Wn  = (const float*)d_in[4];
  const float* an_ = (const float*)d_in[5];
  float* out = (float*)d_out;  // holds h_s, then final output (in-place epilogue)

  unsigned short* HnT = (unsigned short*)d_ws;       // 2 MB (j-block-major)
  float* s = (float*)(HnT + (size_t)128 * NN);       // 8192 f32
  float* n = s + NN;                                 // 8192 f32
  unsigned* P = (unsigned*)(n + NN);                 // 8192*256 uint = 8 MB bitmask

  const size_t base_need = (size_t)128 * NN * 2 + (size_t)2 * NN * 4;
  const size_t bits_need = base_need + (size_t)NN * 256 * 4;

  k_proj<<<1024, 256, 0, stream>>>(X, Ws, Wn, as_, an_, out, HnT, s, n);
  if (ws_size >= bits_need) {
    k_pack<<<8192, 256, 0, stream>>>(A, P);
    k_main_bits<<<512, 512, 0, stream>>>(P, HnT, s, n, out);
  } else {
    k_main_adj<<<512, 512, 0, stream>>>(A, HnT, s, n, out);
  }
}

// Round 6
// 423.675 us; speedup vs baseline: 1.4586x; 1.0417x over previous
//
#include <hip/hip_runtime.h>
#include <math.h>

#define NN 8192
// out = elu(0.5*h_s + (sum_j w_ij h_n_j)/Z_i), w_ij = adj_ij * exp(relu(s_i+n_j))
// Factorization: exp(relu(s+n)) = exp(max(s+n,0)) = max(exp(s)*exp(n), 1)
// (exp monotone) -> precompute es=exp(s), en=exp(n); NO transcendental in the
// O(N^2) inner loop.

typedef short short8 __attribute__((ext_vector_type(8)));   // 8 bf16 (4 VGPRs)
typedef float f32x4 __attribute__((ext_vector_type(4)));

__device__ __forceinline__ float eluf(float x) {
  return x > 0.f ? x : (__expf(x) - 1.f);
}
__device__ __forceinline__ unsigned short f2bf(float f) {
  union { float f; unsigned u; } v; v.f = f;
  unsigned r = v.u + 0x7fffu + ((v.u >> 16) & 1u);  // RNE
  return (unsigned short)(r >> 16);
}
__device__ __forceinline__ unsigned pack4(int4 v, int sh) {
  return ((unsigned)(v.x & 1) << sh) | ((unsigned)(v.y & 1) << (sh + 1)) |
         ((unsigned)(v.z & 1) << (sh + 2)) | ((unsigned)(v.w & 1) << (sh + 3));
}

// ---------------- Kernel 1: projections + fused s/n reductions ----------------
// Verified structure. 8 rows/block, block 256, grid 1024. HnT j-block-major
// [NN/8][128 f][8 j] bf16. Only change vs R5: store exp(s), exp(n).
__global__ __launch_bounds__(256) void k_proj(const float* __restrict__ X,
                                              const float* __restrict__ Ws,
                                              const float* __restrict__ Wn,
                                              const float* __restrict__ as_,
                                              const float* __restrict__ an_,
                                              float* __restrict__ Hs,
                                              unsigned short* __restrict__ HnT,
                                              float* __restrict__ es_out,
                                              float* __restrict__ en_out) {
  __shared__ float4 lin4[8 * 64];  // 8 rows x 256 f32 = 8 KB
  const int t = threadIdx.x;
  const int i0 = blockIdx.x * 8;
  const float4* Xg = (const float4*)X + (size_t)i0 * 64;
  lin4[t] = Xg[t];
  if (t < 256) lin4[t + 256] = Xg[t + 256];
  __syncthreads();
  const int c = t & 127;
  const int rh = t >> 7;  // 0..1, 4 rows each
  float accs[4], accn[4];
#pragma unroll
  for (int r = 0; r < 4; ++r) { accs[r] = 0.f; accn[r] = 0.f; }
  for (int k = 0; k < 256; k += 4) {
    float ws0 = Ws[(k + 0) * 128 + c], ws1 = Ws[(k + 1) * 128 + c];
    float ws2 = Ws[(k + 2) * 128 + c], ws3 = Ws[(k + 3) * 128 + c];
    float wn0 = Wn[(k + 0) * 128 + c], wn1 = Wn[(k + 1) * 128 + c];
    float wn2 = Wn[(k + 2) * 128 + c], wn3 = Wn[(k + 3) * 128 + c];
#pragma unroll
    for (int r = 0; r < 4; ++r) {
      float4 iv = lin4[(rh * 4 + r) * 64 + (k >> 2)];  // wave-uniform broadcast
      accs[r] = fmaf(iv.x, ws0, accs[r]); accs[r] = fmaf(iv.y, ws1, accs[r]);
      accs[r] = fmaf(iv.z, ws2, accs[r]); accs[r] = fmaf(iv.w, ws3, accs[r]);
      accn[r] = fmaf(iv.x, wn0, accn[r]); accn[r] = fmaf(iv.y, wn1, accn[r]);
      accn[r] = fmaf(iv.z, wn2, accn[r]); accn[r] = fmaf(iv.w, wn3, accn[r]);
    }
  }
  // Hs fp32 out
#pragma unroll
  for (int r = 0; r < 4; ++r)
    Hs[(size_t)(i0 + rh * 4 + r) * 128 + c] = accs[r];
  // HnT bf16 out, j-block-major: elem(jb=j/8, f, ji=j%8) at jb*1024 + f*8 + ji.
  {
    union { unsigned short us[4]; ushort4 u4; } pk;
#pragma unroll
    for (int r = 0; r < 4; ++r) pk.us[r] = f2bf(accn[r]);
    *(ushort4*)(HnT + (size_t)blockIdx.x * 1024 + c * 8 + rh * 4) = pk.u4;
  }
  // ---- fused reductions: s[j] = sum_f Hs[j][f]*a_s[f], n likewise; store exp ----
  float* red = (float*)lin4;  // 8 x 128 f32 = 4 KB
  const int wv = t >> 6, ln = t & 63;
  __syncthreads();
  {
    float av = as_[c];
#pragma unroll
    for (int r = 0; r < 4; ++r) red[(rh * 4 + r) * 128 + c] = accs[r] * av;
  }
  __syncthreads();
#pragma unroll
  for (int h = 0; h < 2; ++h) {
    int row = wv * 2 + h;
    float p = red[row * 128 + ln] + red[row * 128 + 64 + ln];
#pragma unroll
    for (int off = 32; off >= 1; off >>= 1) p += __shfl_down(p, off);
    if (ln == 0) es_out[i0 + row] = __expf(p);
  }
  __syncthreads();
  {
    float av = an_[c];
#pragma unroll
    for (int r = 0; r < 4; ++r) red[(rh * 4 + r) * 128 + c] = accn[r] * av;
  }
  __syncthreads();
#pragma unroll
  for (int h = 0; h < 2; ++h) {
    int row = wv * 2 + h;
    float p = red[row * 128 + ln] + red[row * 128 + 64 + ln];
#pragma unroll
    for (int off = 32; off >= 1; off >>= 1) p += __shfl_down(p, off);
    if (ln == 0) en_out[i0 + row] = __expf(p);
  }
}

// ---------------- Kernel 2: fused pack + attention GEMM + softmax + elu ------
// Block 512 (8 waves), 16 rows/block, grid 512. Prologue: stage en (32 KB)
// and pack THIS BLOCK's 16 adj rows (512 KB int32 -> 16 KB bits) directly
// into LDS — k_pack kernel eliminated, adj read exactly once device-wide.
// Steady-state loop (R5-verified schedule): ONE VMEM class (breg = HnT
// f-tiles, L2-resident), zero branches, single-generation breg issued after
// the MFMA block; w = bit ? max(es*en, 1) : 0 — no transcendental.
// Epilogue: two-stage cross-wave combine so LDS = 48.6 KB -> 3 blocks/CU
// (24 waves/CU vs R5's 16) for better latency hiding.
__global__ __launch_bounds__(512, 4) void k_main(const int* __restrict__ A,
                                                 const unsigned short* __restrict__ HnT,
                                                 const float* __restrict__ es_g,
                                                 const float* __restrict__ en_g,
                                                 float* __restrict__ HsOut) {
  __shared__ __align__(16) char smem[49152];           // 48 KB
  float* en_lds = (float*)smem;                        // 8192 f32 = 32 KB (loop)
  unsigned* bits_lds = (unsigned*)(smem + 32768);      // 4096 u32 = 16 KB (loop)
  float* cmb = (float*)smem;                           // 4*16*128 f32 = 32 KB (epilogue)
  __shared__ float zsh[8][16];
  __shared__ float zf[16];

  const int t = threadIdx.x;
  const int wv = t >> 6;   // wave 0..7 = j-partition
  const int ln = t & 63;
  const int q = ln >> 4;   // quad -> k-slice within K=32
  const int m = ln & 15;   // A row / B col / C col
  const int row0 = blockIdx.x * 16;

  // ---- prologue: stage en (8192 f32); pack adj rows row0..row0+15 to bits ----
  {
    float4* dst = (float4*)en_lds;
    const float4* s4 = (const float4*)en_g;
#pragma unroll
    for (int k = 0; k < 4; ++k) dst[t + k * 512] = s4[t + k * 512];
    // word (rr, c8) covers A[row0+rr][c8*32 .. +31]; LDS layout [wv][tt][m]
    // (index (c8>>5)*512 + (c8&31)*16 + rr) = conflict-free loop read.
#pragma unroll 1
    for (int k = 0; k < 8; ++k) {
      int g = t + k * 512;            // 0..4095
      int rr = g >> 8;                // row-in-block 0..15
      int c8 = g & 255;               // word-in-row
      const int4* src = (const int4*)(A + (size_t)(row0 + rr) * NN + c8 * 32);
      int4 v0 = src[0], v1 = src[1], v2 = src[2], v3 = src[3];
      int4 v4 = src[4], v5 = src[5], v6 = src[6], v7 = src[7];
      unsigned w = pack4(v0, 0)  | pack4(v1, 4)  | pack4(v2, 8)  | pack4(v3, 12) |
                   pack4(v4, 16) | pack4(v5, 20) | pack4(v6, 24) | pack4(v7, 28);
      bits_lds[(c8 >> 5) * 512 + (c8 & 31) * 16 + rr] = w;
    }
  }

  const float sme = es_g[row0 + m];
  // HnT elem(jb, f, ji) at jb*1024 + f*8 + ji ; lane base: jb = wv*128 + q, f = m
  const unsigned short* bptr = HnT + ((size_t)(wv * 128 + q) * 128 + m) * 8;
  const float* nvl = en_lds + wv * 1024 + q * 8;       // + tt*32
  const unsigned* bts = bits_lds + wv * 512 + m;       // + tt*16

  f32x4 acc[8];
#pragma unroll
  for (int ft = 0; ft < 8; ++ft) acc[ft] = (f32x4){0.f, 0.f, 0.f, 0.f};
  float zp = 0.f;

  union Breg { uint4 u; short8 s; };
  Breg breg[8];

  __syncthreads();  // LDS stage complete

  // breg(0)
  breg[0].u = *(const uint4*)(bptr);       breg[1].u = *(const uint4*)(bptr + 128);
  breg[2].u = *(const uint4*)(bptr + 256); breg[3].u = *(const uint4*)(bptr + 384);
  breg[4].u = *(const uint4*)(bptr + 512); breg[5].u = *(const uint4*)(bptr + 640);
  breg[6].u = *(const uint4*)(bptr + 768); breg[7].u = *(const uint4*)(bptr + 896);

#pragma unroll 2
  for (int tt = 0; tt < 32; ++tt) {
    // ---- A-frag from LDS: w for rows m, j = wv*1024 + tt*32 + q*8 .. +7 ----
    short8 fr;
    {
      float4 nv0 = *(const float4*)(nvl + tt * 32);
      float4 nv1 = *(const float4*)(nvl + tt * 32 + 4);
      const unsigned bw = bts[tt * 16];
      const unsigned byte = (bw >> (q * 8)) & 0xffu;
      float ev[8] = {nv0.x, nv0.y, nv0.z, nv0.w, nv1.x, nv1.y, nv1.z, nv1.w};
#pragma unroll
      for (int k = 0; k < 8; ++k) {
        float w = ((byte >> k) & 1u) ? fmaxf(sme * ev[k], 1.f) : 0.f;
        zp += w;
        fr[k] = (short)f2bf(w);
      }
    }
    // ---- MFMA: consumes breg(tt) issued last iteration ----
    __builtin_amdgcn_s_setprio(1);
    acc[0] = __builtin_amdgcn_mfma_f32_16x16x32_bf16(fr, breg[0].s, acc[0], 0, 0, 0);
    acc[1] = __builtin_amdgcn_mfma_f32_16x16x32_bf16(fr, breg[1].s, acc[1], 0, 0, 0);
    acc[2] = __builtin_amdgcn_mfma_f32_16x16x32_bf16(fr, breg[2].s, acc[2], 0, 0, 0);
    acc[3] = __builtin_amdgcn_mfma_f32_16x16x32_bf16(fr, breg[3].s, acc[3], 0, 0, 0);
    acc[4] = __builtin_amdgcn_mfma_f32_16x16x32_bf16(fr, breg[4].s, acc[4], 0, 0, 0);
    acc[5] = __builtin_amdgcn_mfma_f32_16x16x32_bf16(fr, breg[5].s, acc[5], 0, 0, 0);
    acc[6] = __builtin_amdgcn_mfma_f32_16x16x32_bf16(fr, breg[6].s, acc[6], 0, 0, 0);
    acc[7] = __builtin_amdgcn_mfma_f32_16x16x32_bf16(fr, breg[7].s, acc[7], 0, 0, 0);
    __builtin_amdgcn_s_setprio(0);
    // ---- issue breg(tt+1), branch-free; tt=31 overruns <=8 KB into the
    // adjacent es/en workspace region (read-only, discarded) ----
    {
      const unsigned short* p = bptr + (size_t)(tt + 1) * 4096;  // +4 j-blocks
      breg[0].u = *(const uint4*)(p);       breg[1].u = *(const uint4*)(p + 128);
      breg[2].u = *(const uint4*)(p + 256); breg[3].u = *(const uint4*)(p + 384);
      breg[4].u = *(const uint4*)(p + 512); breg[5].u = *(const uint4*)(p + 640);
      breg[6].u = *(const uint4*)(p + 768); breg[7].u = *(const uint4*)(p + 896);
    }
  }

  // ---- per-wave Z partial for each row m: reduce over q ----
  {
    float zz = zp;
    zz += __shfl_down(zz, 32);
    zz += __shfl_down(zz, 16);
    if (ln < 16) zsh[wv][ln] = zz;
  }
  __syncthreads();  // all waves done reading en/bits LDS; zsh ready
  // ---- stage 1: waves 4..7 dump partials (32 KB, aliases en/bits) ----
  if (wv >= 4) {
#pragma unroll
    for (int ft = 0; ft < 8; ++ft)
#pragma unroll
      for (int reg = 0; reg < 4; ++reg)
        cmb[(wv - 4) * 2048 + (q * 4 + reg) * 128 + ft * 16 + m] = acc[ft][reg];
  }
  __syncthreads();
  // ---- stage 2: waves 0..3 accumulate partner wave's partials ----
  if (wv < 4) {
#pragma unroll
    for (int ft = 0; ft < 8; ++ft)
#pragma unroll
      for (int reg = 0; reg < 4; ++reg)
        acc[ft][reg] += cmb[wv * 2048 + (q * 4 + reg) * 128 + ft * 16 + m];
  }
  __syncthreads();
  // ---- stage 3: waves 0..3 dump combined partials ----
  if (wv < 4) {
#pragma unroll
    for (int ft = 0; ft < 8; ++ft)
#pragma unroll
      for (int reg = 0; reg < 4; ++reg)
        cmb[wv * 2048 + (q * 4 + reg) * 128 + ft * 16 + m] = acc[ft][reg];
  }
  if (t < 16) {
    float z = zsh[0][t] + zsh[1][t] + zsh[2][t] + zsh[3][t] +
              zsh[4][t] + zsh[5][t] + zsh[6][t] + zsh[7][t];
    zf[t] = 1.f / z;
  }
  __syncthreads();
  // ---- final: 4-way sum + epilogue out = elu(0.5*h_s + acc/Z) ----
  {
    const int row = t >> 5;        // 0..15
    const int f0 = (t & 31) * 4;   // 0..124
    f32x4 ssum = *(const f32x4*)&cmb[row * 128 + f0];
#pragma unroll
    for (int w = 1; w < 4; ++w) ssum += *(const f32x4*)&cmb[w * 2048 + row * 128 + f0];
    const float invz = zf[row];
    const size_t off = (size_t)(row0 + row) * 128 + f0;
    float4 h = *(const float4*)(HsOut + off);
    float4 o;
    o.x = eluf(fmaf(ssum[0], invz, 0.5f * h.x));
    o.y = eluf(fmaf(ssum[1], invz, 0.5f * h.y));
    o.z = eluf(fmaf(ssum[2], invz, 0.5f * h.z));
    o.w = eluf(fmaf(ssum[3], invz, 0.5f * h.w));
    *(float4*)(HsOut + off) = o;
  }
}

extern "C" void kernel_launch(void* const* d_in, const int* in_sizes, int n_in,
                              void* d_out, int out_size, void* d_ws, size_t ws_size,
                              hipStream_t stream) {
  const float* X   = (const float*)d_in[0];
  const int*   A   = (const int*)d_in[1];
  const float* Ws  = (const float*)d_in[2];
  const float* as_ = (const float*)d_in[3];
  const float* Wn  = (const float*)d_in[4];
  const float* an_ = (const float*)d_in[5];
  float* out = (float*)d_out;  // holds h_s, then final output (in-place epilogue)

  unsigned short* HnT = (unsigned short*)d_ws;       // 2 MB (j-block-major)
  float* es = (float*)(HnT + (size_t)128 * NN);      // 8192 f32 = exp(s)
  float* en = es + NN;                               // 8192 f32 = exp(n)

  k_proj<<<1024, 256, 0, stream>>>(X, Ws, Wn, as_, an_, out, HnT, es, en);
  k_main<<<512, 512, 0, stream>>>(A, HnT, es, en, out);
}

// Round 7
// 418.342 us; speedup vs baseline: 1.4772x; 1.0127x over previous
//
#include <hip/hip_runtime.h>
#include <math.h>

#define NN 8192
// out = elu(0.5*h_s + (sum_j w_ij h_n_j)/Z_i), w_ij = adj_ij * exp(relu(s_i+n_j))
// Factorization: exp(relu(s+n)) = max(exp(s)*exp(n), 1) (exp monotone) ->
// precompute es=exp(s), en=exp(n); NO transcendental in the O(N^2) loop.

typedef short short8 __attribute__((ext_vector_type(8)));   // 8 bf16 (4 VGPRs)
typedef float f32x4 __attribute__((ext_vector_type(4)));

__device__ __forceinline__ float eluf(float x) {
  return x > 0.f ? x : (__expf(x) - 1.f);
}
__device__ __forceinline__ unsigned short f2bf(float f) {
  union { float f; unsigned u; } v; v.f = f;
  unsigned r = v.u + 0x7fffu + ((v.u >> 16) & 1u);  // RNE
  return (unsigned short)(r >> 16);
}
__device__ __forceinline__ unsigned pack4(int4 v, int sh) {
  return ((unsigned)(v.x & 1) << sh) | ((unsigned)(v.y & 1) << (sh + 1)) |
         ((unsigned)(v.z & 1) << (sh + 2)) | ((unsigned)(v.w & 1) << (sh + 3));
}

// ---------------- Kernel 1: fused {projections+reductions | adj bit-pack} ----
// Grid 1280 x 256. Role by blockIdx%5: every 5th block streams 32 adj rows ->
// bitmask P (256 blocks, HBM-bound, 256 MB total); the rest run the verified
// proj body (1024 blocks, VALU-bound, ~10 MB). Interleaved roles co-execute,
// hiding proj's compute under pack's HBM stream — no streams/events needed.
__global__ __launch_bounds__(256) void k_pre(const float* __restrict__ X,
                                             const int* __restrict__ A,
                                             const float* __restrict__ Ws,
                                             const float* __restrict__ Wn,
                                             const float* __restrict__ as_,
                                             const float* __restrict__ an_,
                                             float* __restrict__ Hs,
                                             unsigned short* __restrict__ HnT,
                                             float* __restrict__ es_out,
                                             float* __restrict__ en_out,
                                             unsigned* __restrict__ P) {
  __shared__ float4 lin4[8 * 64];  // 8 KB (proj role only)
  const int bid = blockIdx.x;
  const int q5 = bid / 5, r5 = bid - q5 * 5;
  const int t = threadIdx.x;

  if (r5 == 4) {
    // ---- pack role: rows q5*32 .. q5*32+31 -> P[row][j/32] ----
    const int row0 = q5 * 32;
#pragma unroll 1
    for (int k = 0; k < 32; ++k) {
      int g = t + k * 256;            // 0..8191
      int rr = g >> 8;                // 0..31
      int c8 = g & 255;               // word-in-row
      const int4* src = (const int4*)(A + (size_t)(row0 + rr) * NN + c8 * 32);
      int4 v0 = src[0], v1 = src[1], v2 = src[2], v3 = src[3];
      int4 v4 = src[4], v5 = src[5], v6 = src[6], v7 = src[7];
      unsigned w = pack4(v0, 0)  | pack4(v1, 4)  | pack4(v2, 8)  | pack4(v3, 12) |
                   pack4(v4, 16) | pack4(v5, 20) | pack4(v6, 24) | pack4(v7, 28);
      P[(size_t)(row0 + rr) * 256 + c8] = w;
    }
    return;
  }

  // ---- proj role (verified body): 8 rows, i0 = (q5*4+r5)*8 ----
  const int i0 = (q5 * 4 + r5) * 8;
  const float4* Xg = (const float4*)X + (size_t)i0 * 64;
  lin4[t] = Xg[t];
  lin4[t + 256] = Xg[t + 256];
  __syncthreads();
  const int c = t & 127;
  const int rh = t >> 7;  // 0..1, 4 rows each
  float accs[4], accn[4];
#pragma unroll
  for (int r = 0; r < 4; ++r) { accs[r] = 0.f; accn[r] = 0.f; }
  for (int k = 0; k < 256; k += 4) {
    float ws0 = Ws[(k + 0) * 128 + c], ws1 = Ws[(k + 1) * 128 + c];
    float ws2 = Ws[(k + 2) * 128 + c], ws3 = Ws[(k + 3) * 128 + c];
    float wn0 = Wn[(k + 0) * 128 + c], wn1 = Wn[(k + 1) * 128 + c];
    float wn2 = Wn[(k + 2) * 128 + c], wn3 = Wn[(k + 3) * 128 + c];
#pragma unroll
    for (int r = 0; r < 4; ++r) {
      float4 iv = lin4[(rh * 4 + r) * 64 + (k >> 2)];  // wave-uniform broadcast
      accs[r] = fmaf(iv.x, ws0, accs[r]); accs[r] = fmaf(iv.y, ws1, accs[r]);
      accs[r] = fmaf(iv.z, ws2, accs[r]); accs[r] = fmaf(iv.w, ws3, accs[r]);
      accn[r] = fmaf(iv.x, wn0, accn[r]); accn[r] = fmaf(iv.y, wn1, accn[r]);
      accn[r] = fmaf(iv.z, wn2, accn[r]); accn[r] = fmaf(iv.w, wn3, accn[r]);
    }
  }
  // Hs fp32 out
#pragma unroll
  for (int r = 0; r < 4; ++r)
    Hs[(size_t)(i0 + rh * 4 + r) * 128 + c] = accs[r];
  // HnT bf16 out, j-block-major: elem(jb=j/8, f, ji=j%8) at jb*1024 + f*8 + ji.
  {
    union { unsigned short us[4]; ushort4 u4; } pk;
#pragma unroll
    for (int r = 0; r < 4; ++r) pk.us[r] = f2bf(accn[r]);
    *(ushort4*)(HnT + (size_t)(i0 >> 3) * 1024 + c * 8 + rh * 4) = pk.u4;
  }
  // ---- fused reductions -> es = exp(s), en = exp(n) ----
  float* red = (float*)lin4;  // 8 x 128 f32 = 4 KB
  const int wv = t >> 6, ln = t & 63;
  __syncthreads();
  {
    float av = as_[c];
#pragma unroll
    for (int r = 0; r < 4; ++r) red[(rh * 4 + r) * 128 + c] = accs[r] * av;
  }
  __syncthreads();
#pragma unroll
  for (int h = 0; h < 2; ++h) {
    int row = wv * 2 + h;
    float p = red[row * 128 + ln] + red[row * 128 + 64 + ln];
#pragma unroll
    for (int off = 32; off >= 1; off >>= 1) p += __shfl_down(p, off);
    if (ln == 0) es_out[i0 + row] = __expf(p);
  }
  __syncthreads();
  {
    float av = an_[c];
#pragma unroll
    for (int r = 0; r < 4; ++r) red[(rh * 4 + r) * 128 + c] = accn[r] * av;
  }
  __syncthreads();
#pragma unroll
  for (int h = 0; h < 2; ++h) {
    int row = wv * 2 + h;
    float p = red[row * 128 + ln] + red[row * 128 + 64 + ln];
#pragma unroll
    for (int off = 32; off >= 1; off >>= 1) p += __shfl_down(p, off);
    if (ln == 0) en_out[i0 + row] = __expf(p);
  }
}

// ---------------- Kernel 2: attention GEMM + softmax + elu ----------------
// Block 512 (8 waves), 16 rows/block, grid 512. R5-verified structure:
// prologue stages en (32 KB) + bits (16 KB, from global P) into LDS;
// steady-state loop has ONE VMEM class (breg = HnT f-tiles, L2-resident),
// zero branches, single-generation breg issued after the MFMA block.
// w = bit ? max(es*en, 1) : 0 — no transcendental (R6-verified).
// Epilogue: two-stage cross-wave combine, LDS 48 KB total (R6-verified).
__global__ __launch_bounds__(512, 4) void k_main(const unsigned* __restrict__ Pk,
                                                 const unsigned short* __restrict__ HnT,
                                                 const float* __restrict__ es_g,
                                                 const float* __restrict__ en_g,
                                                 float* __restrict__ HsOut) {
  __shared__ __align__(16) char smem[49152];           // 48 KB
  float* en_lds = (float*)smem;                        // 8192 f32 = 32 KB (loop)
  unsigned* bits_lds = (unsigned*)(smem + 32768);      // 4096 u32 = 16 KB (loop)
  float* cmb = (float*)smem;                           // 4*16*128 f32 = 32 KB (epilogue)
  __shared__ float zsh[8][16];
  __shared__ float zf[16];

  const int t = threadIdx.x;
  const int wv = t >> 6;   // wave 0..7 = j-partition
  const int ln = t & 63;
  const int q = ln >> 4;   // quad -> k-slice within K=32
  const int m = ln & 15;   // A row / B col / C col
  const int row0 = blockIdx.x * 16;

  // ---- prologue: stage en (8192 f32) and this block's bits (16x256 u32) ----
  {
    float4* dst = (float4*)en_lds;
    const float4* s4 = (const float4*)en_g;
#pragma unroll
    for (int k = 0; k < 4; ++k) dst[t + k * 512] = s4[t + k * 512];
#pragma unroll
    for (int k = 0; k < 8; ++k) {
      int g = t + k * 512;            // 0..4095
      int rr = g >> 8;                // row-in-block 0..15
      int c8 = g & 255;               // word-in-row
      unsigned w = Pk[(size_t)(row0 + rr) * 256 + c8];
      // LDS layout [wv][tt][m]: conflict-free broadcast read per step
      bits_lds[(c8 >> 5) * 512 + (c8 & 31) * 16 + rr] = w;
    }
  }

  const float sme = es_g[row0 + m];
  // HnT elem(jb, f, ji) at jb*1024 + f*8 + ji ; lane base: jb = wv*128 + q, f = m
  const unsigned short* bptr = HnT + ((size_t)(wv * 128 + q) * 128 + m) * 8;
  const float* nvl = en_lds + wv * 1024 + q * 8;       // + tt*32
  const unsigned* bts = bits_lds + wv * 512 + m;       // + tt*16

  f32x4 acc[8];
#pragma unroll
  for (int ft = 0; ft < 8; ++ft) acc[ft] = (f32x4){0.f, 0.f, 0.f, 0.f};
  float zp = 0.f;

  union Breg { uint4 u; short8 s; };
  Breg breg[8];

  __syncthreads();  // LDS stage complete

  // breg(0)
  breg[0].u = *(const uint4*)(bptr);       breg[1].u = *(const uint4*)(bptr + 128);
  breg[2].u = *(const uint4*)(bptr + 256); breg[3].u = *(const uint4*)(bptr + 384);
  breg[4].u = *(const uint4*)(bptr + 512); breg[5].u = *(const uint4*)(bptr + 640);
  breg[6].u = *(const uint4*)(bptr + 768); breg[7].u = *(const uint4*)(bptr + 896);

#pragma unroll 2
  for (int tt = 0; tt < 32; ++tt) {
    // ---- A-frag from LDS: w for rows m, j = wv*1024 + tt*32 + q*8 .. +7 ----
    short8 fr;
    {
      float4 nv0 = *(const float4*)(nvl + tt * 32);
      float4 nv1 = *(const float4*)(nvl + tt * 32 + 4);
      const unsigned bw = bts[tt * 16];
      const unsigned byte = (bw >> (q * 8)) & 0xffu;
      float ev[8] = {nv0.x, nv0.y, nv0.z, nv0.w, nv1.x, nv1.y, nv1.z, nv1.w};
#pragma unroll
      for (int k = 0; k < 8; ++k) {
        float w = ((byte >> k) & 1u) ? fmaxf(sme * ev[k], 1.f) : 0.f;
        zp += w;
        fr[k] = (short)f2bf(w);
      }
    }
    // ---- MFMA: consumes breg(tt) issued last iteration ----
    __builtin_amdgcn_s_setprio(1);
    acc[0] = __builtin_amdgcn_mfma_f32_16x16x32_bf16(fr, breg[0].s, acc[0], 0, 0, 0);
    acc[1] = __builtin_amdgcn_mfma_f32_16x16x32_bf16(fr, breg[1].s, acc[1], 0, 0, 0);
    acc[2] = __builtin_amdgcn_mfma_f32_16x16x32_bf16(fr, breg[2].s, acc[2], 0, 0, 0);
    acc[3] = __builtin_amdgcn_mfma_f32_16x16x32_bf16(fr, breg[3].s, acc[3], 0, 0, 0);
    acc[4] = __builtin_amdgcn_mfma_f32_16x16x32_bf16(fr, breg[4].s, acc[4], 0, 0, 0);
    acc[5] = __builtin_amdgcn_mfma_f32_16x16x32_bf16(fr, breg[5].s, acc[5], 0, 0, 0);
    acc[6] = __builtin_amdgcn_mfma_f32_16x16x32_bf16(fr, breg[6].s, acc[6], 0, 0, 0);
    acc[7] = __builtin_amdgcn_mfma_f32_16x16x32_bf16(fr, breg[7].s, acc[7], 0, 0, 0);
    __builtin_amdgcn_s_setprio(0);
    // ---- issue breg(tt+1), branch-free; tt=31 overruns <=8 KB into the
    // adjacent es/en workspace region (read-only, discarded) ----
    {
      const unsigned short* p = bptr + (size_t)(tt + 1) * 4096;  // +4 j-blocks
      breg[0].u = *(const uint4*)(p);       breg[1].u = *(const uint4*)(p + 128);
      breg[2].u = *(const uint4*)(p + 256); breg[3].u = *(const uint4*)(p + 384);
      breg[4].u = *(const uint4*)(p + 512); breg[5].u = *(const uint4*)(p + 640);
      breg[6].u = *(const uint4*)(p + 768); breg[7].u = *(const uint4*)(p + 896);
    }
  }

  // ---- per-wave Z partial for each row m: reduce over q ----
  {
    float zz = zp;
    zz += __shfl_down(zz, 32);
    zz += __shfl_down(zz, 16);
    if (ln < 16) zsh[wv][ln] = zz;
  }
  __syncthreads();  // all waves done reading en/bits LDS; zsh ready
  // ---- stage 1: waves 4..7 dump partials (32 KB, aliases en/bits) ----
  if (wv >= 4) {
#pragma unroll
    for (int ft = 0; ft < 8; ++ft)
#pragma unroll
      for (int reg = 0; reg < 4; ++reg)
        cmb[(wv - 4) * 2048 + (q * 4 + reg) * 128 + ft * 16 + m] = acc[ft][reg];
  }
  __syncthreads();
  // ---- stage 2: waves 0..3 accumulate partner wave's partials ----
  if (wv < 4) {
#pragma unroll
    for (int ft = 0; ft < 8; ++ft)
#pragma unroll
      for (int reg = 0; reg < 4; ++reg)
        acc[ft][reg] += cmb[wv * 2048 + (q * 4 + reg) * 128 + ft * 16 + m];
  }
  __syncthreads();
  // ---- stage 3: waves 0..3 dump combined partials ----
  if (wv < 4) {
#pragma unroll
    for (int ft = 0; ft < 8; ++ft)
#pragma unroll
      for (int reg = 0; reg < 4; ++reg)
        cmb[wv * 2048 + (q * 4 + reg) * 128 + ft * 16 + m] = acc[ft][reg];
  }
  if (t < 16) {
    float z = zsh[0][t] + zsh[1][t] + zsh[2][t] + zsh[3][t] +
              zsh[4][t] + zsh[5][t] + zsh[6][t] + zsh[7][t];
    zf[t] = 1.f / z;
  }
  __syncthreads();
  // ---- final: 4-way sum + epilogue out = elu(0.5*h_s + acc/Z) ----
  {
    const int row = t >> 5;        // 0..15
    const int f0 = (t & 31) * 4;   // 0..124
    f32x4 ssum = *(const f32x4*)&cmb[row * 128 + f0];
#pragma unroll
    for (int w = 1; w < 4; ++w) ssum += *(const f32x4*)&cmb[w * 2048 + row * 128 + f0];
    const float invz = zf[row];
    const size_t off = (size_t)(row0 + row) * 128 + f0;
    float4 h = *(const float4*)(HsOut + off);
    float4 o;
    o.x = eluf(fmaf(ssum[0], invz, 0.5f * h.x));
    o.y = eluf(fmaf(ssum[1], invz, 0.5f * h.y));
    o.z = eluf(fmaf(ssum[2], invz, 0.5f * h.z));
    o.w = eluf(fmaf(ssum[3], invz, 0.5f * h.w));
    *(float4*)(HsOut + off) = o;
  }
}

extern "C" void kernel_launch(void* const* d_in, const int* in_sizes, int n_in,
                              void* d_out, int out_size, void* d_ws, size_t ws_size,
                              hipStream_t stream) {
  const float* X   = (const float*)d_in[0];
  const int*   A   = (const int*)d_in[1];
  const float* Ws  = (const float*)d_in[2];
  const float* as_ = (const float*)d_in[3];
  const float* Wn  = (const float*)d_in[4];
  const float* an_ = (const float*)d_in[5];
  float* out = (float*)d_out;  // holds h_s, then final output (in-place epilogue)

  unsigned short* HnT = (unsigned short*)d_ws;       // 2 MB (j-block-major)
  float* es = (float*)(HnT + (size_t)128 * NN);      // 8192 f32 = exp(s)
  float* en = es + NN;                               // 8192 f32 = exp(n)
  unsigned* P = (unsigned*)(en + NN);                // 8 MB bitmask (ws is 1 GiB)

  k_pre<<<1280, 256, 0, stream>>>(X, A, Ws, Wn, as_, an_, out, HnT, es, en, P);
  k_main<<<512, 512, 0, stream>>>(P, HnT, es, en, out);
}